// Round 3
// baseline (158.224 us; speedup 1.0000x reference)
//
#include <hip/hip_runtime.h>

// SparseConv3D gather, v3 — barrier-free tap loop.
//   k0 sp3d_prep : tbl=-1 fill; sp f32->bf16 (spb); W -> frag-major bf16 wb[tap][frag][lane][8]
//   k1 sp3d_build: tbl[o][out_idx] = in_idx (plain stores; out_idx unique per offset)
//   k2 sp3d_main : grid (N/128, 4 cout-blocks), 512 thr = 8 waves x 16 rows x 16 couts.
//                  ALL 27 taps' weight slice (54 KB) staged to LDS once -> single barrier;
//                  each wave loops taps independently, depth-2 pipelined A-gather,
//                  fp32 reg accumulation, one plain store per row. Zero atomics.
// Workspace: spb[N*64 bf16] | wb[27*4096 bf16] | tbl[26*N int]  (~23.6 MB)

typedef __bf16 bf16x8 __attribute__((ext_vector_type(8)));
typedef float f32x4 __attribute__((ext_vector_type(4)));

__device__ __forceinline__ unsigned short f2bf(float f) {
    union { float f; unsigned int u; } v; v.f = f;
    unsigned int u = v.u;
    return (unsigned short)((u + 0x7FFFu + ((u >> 16) & 1u)) >> 16);  // RNE
}

__device__ __forceinline__ ushort4 cvt4(float4 v) {
    ushort4 b;
    b.x = f2bf(v.x); b.y = f2bf(v.y); b.z = f2bf(v.z); b.w = f2bf(v.w);
    return b;
}

// ---- k0: fill tbl=-1, sp->bf16, weights -> frag-major bf16 ----
__global__ __launch_bounds__(256) void sp3d_prep(
    const float* __restrict__ sp, const float* __restrict__ w,
    unsigned short* __restrict__ spb, unsigned short* __restrict__ wb,
    int* __restrict__ tbl, int n_rows)
{
    const long gt = (long)blockIdx.x * 256 + threadIdx.x;
    const long stride = (long)gridDim.x * 256;

    const long ntbl = 26L * n_rows;
    for (long i = gt; i < (ntbl >> 2); i += stride)
        *(int4*)&tbl[i * 4] = make_int4(-1, -1, -1, -1);
    if (gt < (ntbl & 3)) tbl[(ntbl & ~3L) + gt] = -1;

    const long nsp = (long)n_rows * 16;  // float4 chunks
    for (long i = gt; i < nsp; i += stride) {
        float4 v = *(const float4*)&sp[i * 4];
        *(ushort4*)&spb[i * 4] = cvt4(v);
    }

    // wb chunk c (bf16x8): c = tap*512 + frag*64 + lane; frag = nt*2+half
    // value[j] = W[cout=nt*16+ml][cin=half*32+quad*8+j], w layout [cout][27][cin]
    for (long i = gt; i < 27 * 512; i += stride) {
        int tap = (int)(i >> 9);
        int rem = (int)(i & 511);
        int fragid = rem >> 6, lane = rem & 63;
        int nt = fragid >> 1, half = fragid & 1, ml = lane & 15, quad = lane >> 4;
        const float* src = w + (nt * 16 + ml) * 1728 + tap * 64 + half * 32 + quad * 8;
        float4 v0 = *(const float4*)src;
        float4 v1 = *(const float4*)(src + 4);
        *(ushort4*)&wb[i * 8]     = cvt4(v0);
        *(ushort4*)&wb[i * 8 + 4] = cvt4(v1);
    }
}

// ---- k1: scatter-build neighbor table (no conflicts within an offset) ----
__global__ __launch_bounds__(256) void sp3d_build(
    const int* __restrict__ nei, const int* __restrict__ sizes,
    int* __restrict__ tbl, int n_rows, int P)
{
    const int o = blockIdx.y;
    const int p = blockIdx.x * 256 + threadIdx.x;
    if (p < sizes[o]) {
        int2 pr = *(const int2*)&nei[(o * P + p) * 2];   // (out_idx, in_idx)
        tbl[(long)o * n_rows + pr.x] = pr.y;
    }
}

// ---- k2: barrier-free fused gather GEMM, 16 rows x 16 couts per wave ----
__global__ __launch_bounds__(512) void sp3d_main(
    const unsigned short* __restrict__ spb, const unsigned short* __restrict__ wb,
    const float* __restrict__ bias, const int* __restrict__ tbl,
    float* __restrict__ out, int n_rows)
{
    __shared__ unsigned short Bt[27 * 1024];  // all-tap 16-cout weight slice (54 KB)
    __shared__ int tl[26 * 128];              // per-block neighbor slice (13.3 KB)

    const int t = threadIdx.x;
    const int row0 = blockIdx.x * 128;
    const int cb = blockIdx.y;                // cout block (16 couts)
    const int wid = t >> 6, lane = t & 63, ml = lane & 15, quad = lane >> 4;
    const int mrow = wid * 16 + ml;           // local row id 0..127

    // stage all-tap weight slice (contiguous 1 KB run per tap in wb)
    for (int j = t; j < 27 * 128; j += 512) {
        int tap = j >> 7, rem = j & 127;
        *(bf16x8*)&Bt[j * 8] = *(const bf16x8*)(wb + tap * 4096 + cb * 1024 + rem * 8);
    }
    // stage neighbor-table slice (coalesced over rows)
    for (int i = t; i < 26 * 128; i += 512) {
        int o = i >> 7;
        int r = row0 + (i & 127);
        tl[i] = tbl[(long)o * n_rows + (r < n_rows ? r : n_rows - 1)];
    }
    __syncthreads();   // the ONLY barrier

    bf16x8 z8;
    #pragma unroll
    for (int j = 0; j < 8; ++j) z8[j] = (__bf16)0.f;

    f32x4 acc = f32x4{0.f, 0.f, 0.f, 0.f};

    // depth-2 pipelined gather; tp is compile-time after full unroll
    int v0, v1;
    bf16x8 a0 = z8, a1 = z8, na0 = z8, na1 = z8;
    {   // tap 0 (offset 0)
        v0 = tl[mrow];
        if (v0 >= 0) {
            const unsigned short* ap = spb + (long)v0 * 64 + quad * 8;
            a0 = *(const bf16x8*)ap; a1 = *(const bf16x8*)(ap + 32);
        }
        v1 = tl[128 + mrow];  // tap 1 -> offset 1
        if (v1 >= 0) {
            const unsigned short* ap = spb + (long)v1 * 64 + quad * 8;
            na0 = *(const bf16x8*)ap; na1 = *(const bf16x8*)(ap + 32);
        }
    }

    #pragma unroll
    for (int tp = 0; tp < 27; ++tp) {
        // prefetch tap tp+2 (static tap id: center case folds at compile time)
        int v2 = -1;
        bf16x8 f0 = z8, f1 = z8;
        if (tp + 2 < 27) {
            const int tn = tp + 2;
            if (tn == 13) {
                int r = row0 + mrow;
                v2 = (r < n_rows) ? r : n_rows - 1;
            } else {
                const int o = tn - (tn > 13 ? 1 : 0);
                v2 = tl[o * 128 + mrow];
            }
            if (v2 >= 0) {
                const unsigned short* ap = spb + (long)v2 * 64 + quad * 8;
                f0 = *(const bf16x8*)ap; f1 = *(const bf16x8*)(ap + 32);
            }
        }

        if (__any(v0 >= 0)) {
            bf16x8 b0 = *(const bf16x8*)&Bt[tp * 1024 + lane * 8];
            bf16x8 b1 = *(const bf16x8*)&Bt[tp * 1024 + 512 + lane * 8];
            acc = __builtin_amdgcn_mfma_f32_16x16x32_bf16(a0, b0, acc, 0, 0, 0);
            acc = __builtin_amdgcn_mfma_f32_16x16x32_bf16(a1, b1, acc, 0, 0, 0);
        }

        v0 = v1; a0 = na0; a1 = na1;
        v1 = v2; na0 = f0; na1 = f1;
    }

    // epilogue: bias + one store per row (C/D: col=lane&15, row=quad*4+reg)
    const int col = cb * 16 + ml;
    const float bv = bias[col];
    #pragma unroll
    for (int rg = 0; rg < 4; ++rg) {
        int row = row0 + wid * 16 + quad * 4 + rg;
        if (row < n_rows) out[(long)row * 64 + col] = acc[rg] + bv;
    }
}

extern "C" void kernel_launch(void* const* d_in, const int* in_sizes, int n_in,
                              void* d_out, int out_size, void* d_ws, size_t ws_size,
                              hipStream_t stream) {
    const float* sp    = (const float*)d_in[0];
    const float* w     = (const float*)d_in[1];
    const float* bias  = (const float*)d_in[2];
    const int*   nei   = (const int*)d_in[3];
    const int*   sizes = (const int*)d_in[4];
    float* out = (float*)d_out;

    const int N = in_sizes[0] / 64;
    const int P = in_sizes[3] / (26 * 2);

    // workspace carve-out (256B aligned): spb | wb | tbl
    char* ws = (char*)d_ws;
    unsigned short* spb = (unsigned short*)ws;
    size_t off = ((size_t)N * 64 * 2 + 255) & ~(size_t)255;
    unsigned short* wb = (unsigned short*)(ws + off);
    off = (off + 27 * 4096 * 2 + 255) & ~(size_t)255;
    int* tbl = (int*)(ws + off);

    sp3d_prep<<<dim3(2048), 256, 0, stream>>>(sp, w, spb, wb, tbl, N);
    sp3d_build<<<dim3((P + 255) / 256, 26), 256, 0, stream>>>(nei, sizes, tbl, N, P);
    sp3d_main<<<dim3((N + 127) / 128, 4), 512, 0, stream>>>(spb, wb, bias, tbl, out, N);
}

// Round 4
// 141.997 us; speedup vs baseline: 1.1143x; 1.1143x over previous
//
#include <hip/hip_runtime.h>

// SparseConv3D gather, v4 — barrier-free, LDS-free main kernel.
//   k0 sp3d_prep : tbl=-1 fill; sp f32->bf16 (spb); W -> frag-major bf16 wb[tap][frag][lane][8]
//   k1 sp3d_build: tbl[o][out_idx] = in_idx (plain stores; out_idx unique per offset)
//   k2 sp3d_main : 256 thr = 4 waves; each wave owns 16 rows x ALL 64 couts.
//                  27-tap fully-unrolled loop: neighbor idx straight from tbl (1 line/wave/tap),
//                  A gathered from spb (depth-2 prefetch), B-frags straight from global wb
//                  (L1/L2-resident, depth-1 prefetch), 8 MFMAs per executed tap,
//                  __any-skip of empty taps. No LDS, no barriers, zero atomics.
// Workspace: spb[N*64 bf16] | wb[27*4096 bf16] | tbl[26*N int]  (~23.6 MB)

typedef __bf16 bf16x8 __attribute__((ext_vector_type(8)));
typedef float f32x4 __attribute__((ext_vector_type(4)));

__device__ __forceinline__ unsigned short f2bf(float f) {
    union { float f; unsigned int u; } v; v.f = f;
    unsigned int u = v.u;
    return (unsigned short)((u + 0x7FFFu + ((u >> 16) & 1u)) >> 16);  // RNE
}

__device__ __forceinline__ ushort4 cvt4(float4 v) {
    ushort4 b;
    b.x = f2bf(v.x); b.y = f2bf(v.y); b.z = f2bf(v.z); b.w = f2bf(v.w);
    return b;
}

// ---- k0: fill tbl=-1, sp->bf16, weights -> frag-major bf16 ----
__global__ __launch_bounds__(256) void sp3d_prep(
    const float* __restrict__ sp, const float* __restrict__ w,
    unsigned short* __restrict__ spb, unsigned short* __restrict__ wb,
    int* __restrict__ tbl, int n_rows)
{
    const long gt = (long)blockIdx.x * 256 + threadIdx.x;
    const long stride = (long)gridDim.x * 256;

    const long ntbl = 26L * n_rows;
    for (long i = gt; i < (ntbl >> 2); i += stride)
        *(int4*)&tbl[i * 4] = make_int4(-1, -1, -1, -1);
    if (gt < (ntbl & 3)) tbl[(ntbl & ~3L) + gt] = -1;

    const long nsp = (long)n_rows * 16;  // float4 chunks
    for (long i = gt; i < nsp; i += stride) {
        float4 v = *(const float4*)&sp[i * 4];
        *(ushort4*)&spb[i * 4] = cvt4(v);
    }

    // wb chunk c (bf16x8): c = tap*512 + frag*64 + lane; frag = nt*2+half
    // value[j] = W[cout=nt*16+ml][cin=half*32+quad*8+j], w layout [cout][27][cin]
    for (long i = gt; i < 27 * 512; i += stride) {
        int tap = (int)(i >> 9);
        int rem = (int)(i & 511);
        int fragid = rem >> 6, lane = rem & 63;
        int nt = fragid >> 1, half = fragid & 1, ml = lane & 15, quad = lane >> 4;
        const float* src = w + (nt * 16 + ml) * 1728 + tap * 64 + half * 32 + quad * 8;
        float4 v0 = *(const float4*)src;
        float4 v1 = *(const float4*)(src + 4);
        *(ushort4*)&wb[i * 8]     = cvt4(v0);
        *(ushort4*)&wb[i * 8 + 4] = cvt4(v1);
    }
}

// ---- k1: scatter-build neighbor table (no conflicts within an offset) ----
__global__ __launch_bounds__(256) void sp3d_build(
    const int* __restrict__ nei, const int* __restrict__ sizes,
    int* __restrict__ tbl, int n_rows, int P)
{
    const int o = blockIdx.y;
    const int p = blockIdx.x * 256 + threadIdx.x;
    if (p < sizes[o]) {
        int2 pr = *(const int2*)&nei[(o * P + p) * 2];   // (out_idx, in_idx)
        tbl[(long)o * n_rows + pr.x] = pr.y;
    }
}

// ---- k2: barrier-free LDS-free gather GEMM; wave = 16 rows x 64 couts ----
__global__ __launch_bounds__(256) void sp3d_main(
    const unsigned short* __restrict__ spb, const unsigned short* __restrict__ wb,
    const float* __restrict__ bias, const int* __restrict__ tbl,
    float* __restrict__ out, int n_rows)
{
    const int t = threadIdx.x;
    const int wid = t >> 6, lane = t & 63, ml = lane & 15, quad = lane >> 4;
    const int row0 = blockIdx.x * 64;
    const int mrow = row0 + wid * 16 + ml;    // this lane's A-row (global)
    const bool rowok = mrow < n_rows;

    bf16x8 z8;
    #pragma unroll
    for (int j = 0; j < 8; ++j) z8[j] = (__bf16)0.f;

    f32x4 acc[4];
    #pragma unroll
    for (int nt = 0; nt < 4; ++nt) acc[nt] = f32x4{0.f, 0.f, 0.f, 0.f};

    // neighbor index for tap tn (tn compile-time after unroll)
    #define GETV(tn) ((tn) == 13 ? (rowok ? mrow : -1) \
                                 : (rowok ? tbl[(long)((tn) - ((tn) > 13 ? 1 : 0)) * n_rows + mrow] : -1))

    // prologue: A for taps 0,1 ; B for tap 0
    int v0 = GETV(0), v1 = GETV(1);
    bf16x8 a0 = z8, a1 = z8, na0 = z8, na1 = z8;
    if (v0 >= 0) {
        const unsigned short* ap = spb + (long)v0 * 64 + quad * 8;
        a0 = *(const bf16x8*)ap; a1 = *(const bf16x8*)(ap + 32);
    }
    if (v1 >= 0) {
        const unsigned short* ap = spb + (long)v1 * 64 + quad * 8;
        na0 = *(const bf16x8*)ap; na1 = *(const bf16x8*)(ap + 32);
    }
    bf16x8 b[8], nb[8];
    if (__any(v0 >= 0)) {
        #pragma unroll
        for (int j = 0; j < 8; ++j) b[j] = *(const bf16x8*)(wb + j * 512 + lane * 8);
    }

    #pragma unroll
    for (int tp = 0; tp < 27; ++tp) {
        // prefetch A for tap tp+2 (depth 2: covers L3/HBM gather latency)
        int v2 = -1;
        bf16x8 f0 = z8, f1 = z8;
        if (tp + 2 < 27) {
            v2 = GETV(tp + 2);
            if (v2 >= 0) {
                const unsigned short* ap = spb + (long)v2 * 64 + quad * 8;
                f0 = *(const bf16x8*)ap; f1 = *(const bf16x8*)(ap + 32);
            }
        }
        // prefetch B for tap tp+1 (L1/L2-resident, depth 1)
        if (tp + 1 < 27 && __any(v1 >= 0)) {
            #pragma unroll
            for (int j = 0; j < 8; ++j)
                nb[j] = *(const bf16x8*)(wb + (tp + 1) * 4096 + j * 512 + lane * 8);
        }
        // compute tap tp
        if (__any(v0 >= 0)) {
            #pragma unroll
            for (int nt = 0; nt < 4; ++nt) {
                acc[nt] = __builtin_amdgcn_mfma_f32_16x16x32_bf16(a0, b[nt * 2 + 0], acc[nt], 0, 0, 0);
                acc[nt] = __builtin_amdgcn_mfma_f32_16x16x32_bf16(a1, b[nt * 2 + 1], acc[nt], 0, 0, 0);
            }
        }
        // rotate (virtual: full unroll -> register renaming, no real movs)
        v0 = v1; a0 = na0; a1 = na1;
        v1 = v2; na0 = f0; na1 = f1;
        #pragma unroll
        for (int j = 0; j < 8; ++j) b[j] = nb[j];
    }
    #undef GETV

    // epilogue: bias + one plain store per element (C/D: col=lane&15, row=quad*4+reg)
    #pragma unroll
    for (int nt = 0; nt < 4; ++nt) {
        int col = nt * 16 + ml;
        float bv = bias[col];
        #pragma unroll
        for (int rg = 0; rg < 4; ++rg) {
            int row = row0 + wid * 16 + quad * 4 + rg;
            if (row < n_rows) out[(long)row * 64 + col] = acc[nt][rg] + bv;
        }
    }
}

extern "C" void kernel_launch(void* const* d_in, const int* in_sizes, int n_in,
                              void* d_out, int out_size, void* d_ws, size_t ws_size,
                              hipStream_t stream) {
    const float* sp    = (const float*)d_in[0];
    const float* w     = (const float*)d_in[1];
    const float* bias  = (const float*)d_in[2];
    const int*   nei   = (const int*)d_in[3];
    const int*   sizes = (const int*)d_in[4];
    float* out = (float*)d_out;

    const int N = in_sizes[0] / 64;
    const int P = in_sizes[3] / (26 * 2);

    // workspace carve-out (256B aligned): spb | wb | tbl
    char* ws = (char*)d_ws;
    unsigned short* spb = (unsigned short*)ws;
    size_t off = ((size_t)N * 64 * 2 + 255) & ~(size_t)255;
    unsigned short* wb = (unsigned short*)(ws + off);
    off = (off + 27 * 4096 * 2 + 255) & ~(size_t)255;
    int* tbl = (int*)(ws + off);

    sp3d_prep<<<dim3(2048), 256, 0, stream>>>(sp, w, spb, wb, tbl, N);
    sp3d_build<<<dim3((P + 255) / 256, 26), 256, 0, stream>>>(nei, sizes, tbl, N, P);
    sp3d_main<<<dim3((N + 63) / 64), 256, 0, stream>>>(spb, wb, bias, tbl, out, N);
}